// Round 4
// baseline (572.360 us; speedup 1.0000x reference)
//
#include <hip/hip_runtime.h>
#include <hip/hip_bf16.h>
#include <cstdint>
#include <cstddef>

#define H 96
#define W 96
#define HW 9216
#define C 256
#define B 8
#define O 256
#define KK 9
#define EPS 1e-5f

typedef __attribute__((ext_vector_type(8))) short short8;
typedef __attribute__((ext_vector_type(4))) float float4v;
typedef unsigned short ushort_t;
typedef unsigned int uint_t;

// ---------------- Kernel 1: transpose x (B,C,HW) fp32 -> x_t (B,HW,C) bf16
__global__ __launch_bounds__(256) void transpose_x_k(
    const float* __restrict__ x, ushort_t* __restrict__ xt)
{
    __shared__ float tile[64][65];
    int t = threadIdx.x;
    int p0 = blockIdx.x * 64;
    int c0 = blockIdx.y * 64;
    int b  = blockIdx.z;
    {
        int tx = t & 63, ty = t >> 6;   // ty 0..3
        const float* xb = x + ((size_t)b * C + c0 + ty) * HW + p0 + tx;
#pragma unroll
        for (int i = 0; i < 64; i += 4)
            tile[ty + i][tx] = xb[(size_t)i * HW];
    }
    __syncthreads();
    {
        int tc = t & 31, tp = t >> 5;   // tc: c-pair 0..31, tp: row 0..7
        ushort_t* xtb = xt + ((size_t)b * HW + p0) * C + c0;
#pragma unroll
        for (int i = 0; i < 64; i += 8) {
            int p = tp + i;
            float a  = tile[2 * tc][p];
            float bb = tile[2 * tc + 1][p];
            __hip_bfloat162 h2 = __float22bfloat162_rn(make_float2(a, bb));
            uint_t u;
            __builtin_memcpy(&u, &h2, 4);
            *reinterpret_cast<uint_t*>(&xtb[(size_t)p * C + 2 * tc]) = u;
        }
    }
}

// ---------------- Kernel 2: w_dcn (O, C, KK) fp32 -> Bp[kk][o][c] bf16
__global__ __launch_bounds__(256) void prep_b_k(
    const float* __restrict__ wd, ushort_t* __restrict__ bp)
{
    int idx = blockIdx.x * 256 + threadIdx.x;
    int kk = idx / (O * C);
    int r = idx - kk * O * C;
    int o = r >> 8, c = r & 255;
    float v = wd[((size_t)o * C + c) * KK + kk];
    __hip_bfloat16 hh = __float2bfloat16(v);
    ushort_t u;
    __builtin_memcpy(&u, &hh, 2);
    bp[idx] = u;
}

// ---------------- Kernel 3: w_off (27, C, 3, 3) fp32 -> bo[n=32][kk][c] bf16
__global__ __launch_bounds__(256) void prep_bo_k(
    const float* __restrict__ wo, ushort_t* __restrict__ bo)
{
    int idx = blockIdx.x * 256 + threadIdx.x;
    int n = idx / (KK * C);
    int r = idx - n * KK * C;
    int kk = r >> 8, c = r & 255;
    float v = (n < 27) ? wo[((size_t)n * C + c) * KK + kk] : 0.0f;
    __hip_bfloat16 hh = __float2bfloat16(v);
    ushort_t u;
    __builtin_memcpy(&u, &hh, 2);
    bo[idx] = u;
}

// ---------------- Kernel 4: offset conv via MFMA (XCD-swizzled)
__global__ __launch_bounds__(256) void offset_mfma_k(
    const ushort_t* __restrict__ xt, const ushort_t* __restrict__ bo,
    const float* __restrict__ b_off, float* __restrict__ om)
{
    int t = threadIdx.x;
    int wv = t >> 6, l = t & 63;
    int ln = l & 15, lq = l >> 4;
    int d = blockIdx.x;                      // 576 = 8 XCD * 72 (one batch each)
    int lb = (d & 7) * 72 + (d >> 3);
    int p0 = lb * 128;
    int b = p0 / HW;
    int rem0w = p0 - b * HW + wv * 32;
    const ushort_t* xtb = xt + (size_t)b * HW * C;

    int hh0[2], ww0[2];
#pragma unroll
    for (int mt = 0; mt < 2; ++mt) {
        int rem = rem0w + mt * 16 + ln;
        hh0[mt] = rem / W;
        ww0[mt] = rem - hh0[mt] * W;
    }

    float4v acc[2][2];
#pragma unroll
    for (int i = 0; i < 2; ++i)
#pragma unroll
        for (int j = 0; j < 2; ++j) acc[i][j] = (float4v){0.f, 0.f, 0.f, 0.f};

#pragma unroll
    for (int kk = 0; kk < KK; ++kk) {
        int dy = kk / 3 - 1, dx = kk % 3 - 1;
        const ushort_t* ap[2];
        bool okv[2];
#pragma unroll
        for (int mt = 0; mt < 2; ++mt) {
            int hh = hh0[mt] + dy, ww = ww0[mt] + dx;
            okv[mt] = (hh >= 0) & (hh < H) & (ww >= 0) & (ww < W);
            ap[mt] = xtb + (size_t)(hh * W + ww) * C + lq * 8;
        }
        const ushort_t* bp0 = bo + ((size_t)(0 * 16 + ln) * KK + kk) * C + lq * 8;
        const ushort_t* bp1 = bo + ((size_t)(1 * 16 + ln) * KK + kk) * C + lq * 8;
#pragma unroll
        for (int cc = 0; cc < 8; ++cc) {
            int c0 = cc * 32;
            short8 af[2];
#pragma unroll
            for (int mt = 0; mt < 2; ++mt) {
                short8 v = (short8)0;
                if (okv[mt]) v = *(const short8*)(ap[mt] + c0);
                af[mt] = v;
            }
            short8 bf0 = *(const short8*)(bp0 + c0);
            short8 bf1 = *(const short8*)(bp1 + c0);
#pragma unroll
            for (int mt = 0; mt < 2; ++mt) {
                acc[mt][0] = __builtin_amdgcn_mfma_f32_16x16x32_bf16(af[mt], bf0, acc[mt][0], 0, 0, 0);
                acc[mt][1] = __builtin_amdgcn_mfma_f32_16x16x32_bf16(af[mt], bf1, acc[mt][1], 0, 0, 0);
            }
        }
    }

    float* omb = om + (size_t)b * 27 * HW + rem0w;
#pragma unroll
    for (int nt = 0; nt < 2; ++nt) {
        int oc = nt * 16 + ln;
        if (oc < 27) {
            float bv = b_off[oc];
            float* po = omb + (size_t)oc * HW + lq * 4;
#pragma unroll
            for (int mt = 0; mt < 2; ++mt) {
                float4 v;
                v.x = acc[mt][nt].x + bv;
                v.y = acc[mt][nt].y + bv;
                v.z = acc[mt][nt].z + bv;
                v.w = acc[mt][nt].w + bv;
                *(float4*)(po + mt * 16) = v;
            }
        }
    }
}

__device__ __forceinline__ void unpack8(uint4 q, float* v) {
    v[0] = __uint_as_float(q.x << 16);
    v[1] = __uint_as_float(q.x & 0xffff0000u);
    v[2] = __uint_as_float(q.y << 16);
    v[3] = __uint_as_float(q.y & 0xffff0000u);
    v[4] = __uint_as_float(q.z << 16);
    v[5] = __uint_as_float(q.z & 0xffff0000u);
    v[6] = __uint_as_float(q.w << 16);
    v[7] = __uint_as_float(q.w & 0xffff0000u);
}

__device__ __forceinline__ uint_t packbf2(float a, float b) {
    __hip_bfloat162 h2 = __float22bfloat162_rn(make_float2(a, b));
    uint_t u;
    __builtin_memcpy(&u, &h2, 4);
    return u;
}

// ---------------- Kernel 5: deformable conv main (MFMA, pipelined, swizzled)
// M=64 px/block, N=256. Phase = 64 channels; 36 phases, dbuf LDS, 1 barrier/phase.
__global__ __launch_bounds__(256) void dcn_main_k(
    const ushort_t* __restrict__ xt, const float* __restrict__ om,
    const ushort_t* __restrict__ bp, const float* __restrict__ b_dcn,
    const float* __restrict__ gamma, const float* __restrict__ beta,
    const float* __restrict__ rmean, const float* __restrict__ rvar,
    float* __restrict__ out)
{
    __shared__ uint4    s_rec0[64 * KK];        // [kk*64+m]: off0,off1,w00,w01  9216B
    __shared__ float2   s_rec1[64 * KK];        // [kk*64+m]: w10,w11            4608B
    __shared__ ushort_t s_a[2][2][64][32];      // [buf][j][m][c]               16384B

    int t = threadIdx.x;
    int d = blockIdx.x;                         // 1152 = 8 XCD * 144 (one batch each)
    int lb = (d & 7) * 144 + (d >> 3);
    int p0 = lb * 64;
    int b = p0 / HW;
    int rem0 = p0 - b * HW;

    // ---- bilinear records, indexed [kk*64 + m] (lane stride 16B -> conflict-free)
    for (int v = t; v < 64 * KK; v += 256) {
        int m = v & 63;
        int k = v >> 6;
        int rem = rem0 + m;
        int h = rem / W;
        int w = rem - h * W;
        const float* omb = om + (size_t)b * 27 * HW + rem;
        float offy = omb[(size_t)(2 * k) * HW];
        float offx = omb[(size_t)(2 * k + 1) * HW];
        float z    = omb[(size_t)(18 + k) * HW];
        float mval = 1.0f / (1.0f + __expf(-z));
        float py = (float)(h + k / 3 - 1) + offy;
        float px = (float)(w + k % 3 - 1) + offx;
        float fy = floorf(py), fx = floorf(px);
        int y0 = (int)fy, x0 = (int)fx;
        float wy = py - fy, wx = px - fx;
        float row0f = (1.0f - wy) * mval * ((y0 >= 0 && y0 < H) ? 1.0f : 0.0f);
        float row1f = wy * mval * ((y0 >= -1 && y0 < H - 1) ? 1.0f : 0.0f);
        int xsel = min(max(x0, 0), W - 2);
        float wxa = (x0 >= 0 && x0 < W) ? (1.0f - wx) : 0.0f;
        float wxb = (x0 >= -1 && x0 < W - 1) ? wx : 0.0f;
        int cx0 = min(max(x0, 0), W - 1);
        int cx1 = min(max(x0 + 1, 0), W - 1);
        float wA = ((cx0 == xsel) ? wxa : 0.0f) + ((cx1 == xsel) ? wxb : 0.0f);
        float wB = ((cx0 == xsel + 1) ? wxa : 0.0f) + ((cx1 == xsel + 1) ? wxb : 0.0f);
        int yc0 = min(max(y0, 0), H - 1);
        int yc1 = min(max(y0 + 1, 0), H - 1);
        uint4 r0;
        r0.x = (uint_t)((yc0 * W + xsel) * C);
        r0.y = (uint_t)((yc1 * W + xsel) * C);
        r0.z = __float_as_uint(row0f * wA);
        r0.w = __float_as_uint(row0f * wB);
        s_rec0[v] = r0;
        s_rec1[v] = make_float2(row1f * wA, row1f * wB);
    }

    float4v acc[4][4];
#pragma unroll
    for (int i = 0; i < 4; ++i)
#pragma unroll
        for (int j = 0; j < 4; ++j)
            acc[i][j] = (float4v){0.f, 0.f, 0.f, 0.f};

    const ushort_t* xtb = xt + (size_t)b * HW * C;
    int wv = t >> 6;          // wave -> n block (wv*64)
    int l  = t & 63;
    int ln = l & 15;
    int lq = l >> 4;
    int m  = t & 63;          // staging pixel
    int g  = t >> 6;          // staging channel octet
    int coff = g * 8;

    __syncthreads();

    // pipeline: L holds loads for phase `it`; issue next phase before MFMA of current
    uint4 L[8];
    float Wt[4];
    {
        // issue phase 0 (kk=0, q=0)
        uint4 r0 = s_rec0[m];           // kk=0
        float2 r1 = s_rec1[m];
        const ushort_t* q0 = xtb + r0.x + coff;
        const ushort_t* q1 = xtb + r0.y + coff;
        Wt[0] = __uint_as_float(r0.z); Wt[1] = __uint_as_float(r0.w);
        Wt[2] = r1.x; Wt[3] = r1.y;
#pragma unroll
        for (int j = 0; j < 2; ++j) {
            L[j * 4 + 0] = *(const uint4*)(q0 + j * 32);
            L[j * 4 + 1] = *(const uint4*)(q0 + C + j * 32);
            L[j * 4 + 2] = *(const uint4*)(q1 + j * 32);
            L[j * 4 + 3] = *(const uint4*)(q1 + C + j * 32);
        }
    }

    for (int it = 0; it < 36; ++it) {
        int kk = it >> 2, q = it & 3;
        int buf = it & 1;

        // ---- combine current phase into pk
        uint4 pk[2];
#pragma unroll
        for (int j = 0; j < 2; ++j) {
            float v0[8], v1[8], v2[8], v3[8], val[8];
            unpack8(L[j * 4 + 0], v0); unpack8(L[j * 4 + 1], v1);
            unpack8(L[j * 4 + 2], v2); unpack8(L[j * 4 + 3], v3);
#pragma unroll
            for (int e = 0; e < 8; ++e)
                val[e] = v0[e] * Wt[0] + v1[e] * Wt[1] + v2[e] * Wt[2] + v3[e] * Wt[3];
            pk[j].x = packbf2(val[0], val[1]);
            pk[j].y = packbf2(val[2], val[3]);
            pk[j].z = packbf2(val[4], val[5]);
            pk[j].w = packbf2(val[6], val[7]);
        }

        // ---- issue loads for next phase (overlaps barrier + MFMA below)
        int nit = it + 1;
        if (nit < 36) {
            int nkk = nit >> 2, nq = nit & 3;
            uint4 r0 = s_rec0[nkk * 64 + m];
            float2 r1 = s_rec1[nkk * 64 + m];
            const ushort_t* q0 = xtb + r0.x + nq * 64 + coff;
            const ushort_t* q1 = xtb + r0.y + nq * 64 + coff;
            Wt[0] = __uint_as_float(r0.z); Wt[1] = __uint_as_float(r0.w);
            Wt[2] = r1.x; Wt[3] = r1.y;
#pragma unroll
            for (int j = 0; j < 2; ++j) {
                L[j * 4 + 0] = *(const uint4*)(q0 + j * 32);
                L[j * 4 + 1] = *(const uint4*)(q0 + C + j * 32);
                L[j * 4 + 2] = *(const uint4*)(q1 + j * 32);
                L[j * 4 + 3] = *(const uint4*)(q1 + C + j * 32);
            }
        }

        // ---- publish A tile
        *(uint4*)&s_a[buf][0][m][coff] = pk[0];
        *(uint4*)&s_a[buf][1][m][coff] = pk[1];
        __syncthreads();

        // ---- MFMA phase: 2 chunks x 16 = 32 MFMAs per wave
#pragma unroll
        for (int j = 0; j < 2; ++j) {
            short8 bfr[4], af[4];
#pragma unroll
            for (int nt = 0; nt < 4; ++nt)
                bfr[nt] = *(const short8*)(bp + ((size_t)kk * O + wv * 64 + nt * 16 + ln) * C
                                           + q * 64 + j * 32 + lq * 8);
#pragma unroll
            for (int mt = 0; mt < 4; ++mt)
                af[mt] = *(const short8*)&s_a[buf][j][mt * 16 + ln][lq * 8];
#pragma unroll
            for (int mt = 0; mt < 4; ++mt)
#pragma unroll
                for (int nt = 0; nt < 4; ++nt)
                    acc[mt][nt] = __builtin_amdgcn_mfma_f32_16x16x32_bf16(
                        af[mt], bfr[nt], acc[mt][nt], 0, 0, 0);
        }
    }

    // ---- epilogue: bias + BN + ReLU
#pragma unroll
    for (int nt = 0; nt < 4; ++nt) {
        int o = wv * 64 + nt * 16 + ln;
        float scale = gamma[o] * rsqrtf(rvar[o] + EPS);
        float shift = (b_dcn[o] - rmean[o]) * scale + beta[o];
        float* po = out + ((size_t)b * O + o) * HW + rem0 + lq * 4;
#pragma unroll
        for (int mt = 0; mt < 4; ++mt) {
            float4 vv;
            vv.x = fmaxf(acc[mt][nt].x * scale + shift, 0.0f);
            vv.y = fmaxf(acc[mt][nt].y * scale + shift, 0.0f);
            vv.z = fmaxf(acc[mt][nt].z * scale + shift, 0.0f);
            vv.w = fmaxf(acc[mt][nt].w * scale + shift, 0.0f);
            *(float4*)(po + mt * 16) = vv;
        }
    }
}

extern "C" void kernel_launch(void* const* d_in, const int* in_sizes, int n_in,
                              void* d_out, int out_size, void* d_ws, size_t ws_size,
                              hipStream_t stream) {
    const float* x     = (const float*)d_in[0];
    const float* w_off = (const float*)d_in[1];
    const float* b_off = (const float*)d_in[2];
    const float* w_dcn = (const float*)d_in[3];
    const float* b_dcn = (const float*)d_in[4];
    const float* gamma = (const float*)d_in[5];
    const float* beta  = (const float*)d_in[6];
    const float* rmean = (const float*)d_in[7];
    const float* rvar  = (const float*)d_in[8];
    float* out = (float*)d_out;

    float*    om  = (float*)d_ws;                          // 1,990,656 f (7.96 MB)
    ushort_t* bpw = (ushort_t*)(om + (size_t)B * 27 * HW); // 589,824 us (1.18 MB)
    ushort_t* bow = bpw + (size_t)KK * O * C;              // 73,728 us (147 KB)
    ushort_t* xtw = bow + (size_t)32 * KK * C;             // 18,874,368 us (37.7 MB)

    hipLaunchKernelGGL(transpose_x_k, dim3(144, 4, 8), dim3(256), 0, stream,
                       x, xtw);
    hipLaunchKernelGGL(prep_b_k, dim3(2304), dim3(256), 0, stream,
                       w_dcn, bpw);
    hipLaunchKernelGGL(prep_bo_k, dim3(288), dim3(256), 0, stream,
                       w_off, bow);
    hipLaunchKernelGGL(offset_mfma_k, dim3(73728 / 128), dim3(256), 0, stream,
                       xtw, bow, b_off, om);
    hipLaunchKernelGGL(dcn_main_k, dim3(73728 / 64), dim3(256), 0, stream,
                       xtw, om, bpw, b_dcn, gamma, beta, rmean, rvar, out);
}

// Round 5
// 476.844 us; speedup vs baseline: 1.2003x; 1.2003x over previous
//
#include <hip/hip_runtime.h>
#include <hip/hip_bf16.h>
#include <cstdint>
#include <cstddef>

#define H 96
#define W 96
#define HW 9216
#define C 256
#define B 8
#define O 256
#define KK 9
#define EPS 1e-5f

typedef __attribute__((ext_vector_type(8))) short short8;
typedef __attribute__((ext_vector_type(4))) float float4v;
typedef unsigned short ushort_t;
typedef unsigned int uint_t;

// ---------------- Kernel 1: transpose x (B,C,HW) fp32 -> x_t (B,HW,C) bf16
__global__ __launch_bounds__(256) void transpose_x_k(
    const float* __restrict__ x, ushort_t* __restrict__ xt)
{
    __shared__ float tile[64][65];
    int t = threadIdx.x;
    int p0 = blockIdx.x * 64;
    int c0 = blockIdx.y * 64;
    int b  = blockIdx.z;
    {
        int tx = t & 63, ty = t >> 6;
        const float* xb = x + ((size_t)b * C + c0 + ty) * HW + p0 + tx;
#pragma unroll
        for (int i = 0; i < 64; i += 4)
            tile[ty + i][tx] = xb[(size_t)i * HW];
    }
    __syncthreads();
    {
        int tc = t & 31, tp = t >> 5;
        ushort_t* xtb = xt + ((size_t)b * HW + p0) * C + c0;
#pragma unroll
        for (int i = 0; i < 64; i += 8) {
            int p = tp + i;
            float a  = tile[2 * tc][p];
            float bb = tile[2 * tc + 1][p];
            __hip_bfloat162 h2 = __float22bfloat162_rn(make_float2(a, bb));
            uint_t u;
            __builtin_memcpy(&u, &h2, 4);
            *reinterpret_cast<uint_t*>(&xtb[(size_t)p * C + 2 * tc]) = u;
        }
    }
}

// ---------------- Kernel 2: w_dcn (O, C, KK) fp32 -> Bp[kk][o][c] bf16
__global__ __launch_bounds__(256) void prep_b_k(
    const float* __restrict__ wd, ushort_t* __restrict__ bp)
{
    int idx = blockIdx.x * 256 + threadIdx.x;
    int kk = idx / (O * C);
    int r = idx - kk * O * C;
    int o = r >> 8, c = r & 255;
    float v = wd[((size_t)o * C + c) * KK + kk];
    __hip_bfloat16 hh = __float2bfloat16(v);
    ushort_t u;
    __builtin_memcpy(&u, &hh, 2);
    bp[idx] = u;
}

// ---------------- Kernel 3: w_off (27, C, 3, 3) fp32 -> bo[n=32][kk][c] bf16
__global__ __launch_bounds__(256) void prep_bo_k(
    const float* __restrict__ wo, ushort_t* __restrict__ bo)
{
    int idx = blockIdx.x * 256 + threadIdx.x;
    int n = idx / (KK * C);
    int r = idx - n * KK * C;
    int kk = r >> 8, c = r & 255;
    float v = (n < 27) ? wo[((size_t)n * C + c) * KK + kk] : 0.0f;
    __hip_bfloat16 hh = __float2bfloat16(v);
    ushort_t u;
    __builtin_memcpy(&u, &hh, 2);
    bo[idx] = u;
}

// ---------------- Kernel 4: offset conv via MFMA (XCD-swizzled, branch-free loads)
__global__ __launch_bounds__(256) void offset_mfma_k(
    const ushort_t* __restrict__ xt, const ushort_t* __restrict__ bo,
    const float* __restrict__ b_off, float* __restrict__ om)
{
    int t = threadIdx.x;
    int wv = t >> 6, l = t & 63;
    int ln = l & 15, lq = l >> 4;
    int d = blockIdx.x;                      // 576 = 8 XCD * 72 (one batch each)
    int lb = (d & 7) * 72 + (d >> 3);
    int p0 = lb * 128;
    int b = p0 / HW;
    int rem0w = p0 - b * HW + wv * 32;
    const ushort_t* xtb = xt + (size_t)b * HW * C;

    int hh0[2], ww0[2];
#pragma unroll
    for (int mt = 0; mt < 2; ++mt) {
        int rem = rem0w + mt * 16 + ln;
        hh0[mt] = rem / W;
        ww0[mt] = rem - hh0[mt] * W;
    }

    float4v acc[2][2];
#pragma unroll
    for (int i = 0; i < 2; ++i)
#pragma unroll
        for (int j = 0; j < 2; ++j) acc[i][j] = (float4v){0.f, 0.f, 0.f, 0.f};

#pragma unroll
    for (int kk = 0; kk < KK; ++kk) {
        int dy = kk / 3 - 1, dx = kk % 3 - 1;
        const ushort_t* ap[2];
        uint_t msk[2];
#pragma unroll
        for (int mt = 0; mt < 2; ++mt) {
            int hh = hh0[mt] + dy, ww = ww0[mt] + dx;
            bool ok = (hh >= 0) & (hh < H) & (ww >= 0) & (ww < W);
            msk[mt] = ok ? 0xffffffffu : 0u;
            int hc = min(max(hh, 0), H - 1);
            int wc = min(max(ww, 0), W - 1);
            ap[mt] = xtb + (size_t)(hc * W + wc) * C + lq * 8;
        }
        const ushort_t* bp0 = bo + ((size_t)(0 * 16 + ln) * KK + kk) * C + lq * 8;
        const ushort_t* bp1 = bo + ((size_t)(1 * 16 + ln) * KK + kk) * C + lq * 8;
#pragma unroll
        for (int cc = 0; cc < 8; ++cc) {
            int c0 = cc * 32;
            short8 af[2];
#pragma unroll
            for (int mt = 0; mt < 2; ++mt) {
                uint4 u = *(const uint4*)(ap[mt] + c0);   // unconditional -> hoistable
                u.x &= msk[mt]; u.y &= msk[mt]; u.z &= msk[mt]; u.w &= msk[mt];
                __builtin_memcpy(&af[mt], &u, 16);
            }
            short8 bf0 = *(const short8*)(bp0 + c0);
            short8 bf1 = *(const short8*)(bp1 + c0);
#pragma unroll
            for (int mt = 0; mt < 2; ++mt) {
                acc[mt][0] = __builtin_amdgcn_mfma_f32_16x16x32_bf16(af[mt], bf0, acc[mt][0], 0, 0, 0);
                acc[mt][1] = __builtin_amdgcn_mfma_f32_16x16x32_bf16(af[mt], bf1, acc[mt][1], 0, 0, 0);
            }
        }
    }

    float* omb = om + (size_t)b * 27 * HW + rem0w;
#pragma unroll
    for (int nt = 0; nt < 2; ++nt) {
        int oc = nt * 16 + ln;
        if (oc < 27) {
            float bv = b_off[oc];
            float* po = omb + (size_t)oc * HW + lq * 4;
#pragma unroll
            for (int mt = 0; mt < 2; ++mt) {
                float4 v;
                v.x = acc[mt][nt].x + bv;
                v.y = acc[mt][nt].y + bv;
                v.z = acc[mt][nt].z + bv;
                v.w = acc[mt][nt].w + bv;
                *(float4*)(po + mt * 16) = v;
            }
        }
    }
}

__device__ __forceinline__ void unpack8(uint4 q, float* v) {
    v[0] = __uint_as_float(q.x << 16);
    v[1] = __uint_as_float(q.x & 0xffff0000u);
    v[2] = __uint_as_float(q.y << 16);
    v[3] = __uint_as_float(q.y & 0xffff0000u);
    v[4] = __uint_as_float(q.z << 16);
    v[5] = __uint_as_float(q.z & 0xffff0000u);
    v[6] = __uint_as_float(q.w << 16);
    v[7] = __uint_as_float(q.w & 0xffff0000u);
}

__device__ __forceinline__ uint_t packbf2(float a, float b) {
    __hip_bfloat162 h2 = __float22bfloat162_rn(make_float2(a, b));
    uint_t u;
    __builtin_memcpy(&u, &h2, 4);
    return u;
}

// ---------------- Kernel 5: deformable conv main
// Loop body: barrier -> issue A(it+1) -> MFMA(it) -> combine(it+1) -> LDS write.
// A-loads are in flight across the whole MFMA section; the barrier's vmcnt(0)
// drain sees only already-consumed loads (cheap).
__global__ __launch_bounds__(256) void dcn_main_k(
    const ushort_t* __restrict__ xt, const float* __restrict__ om,
    const ushort_t* __restrict__ bp, const float* __restrict__ b_dcn,
    const float* __restrict__ gamma, const float* __restrict__ beta,
    const float* __restrict__ rmean, const float* __restrict__ rvar,
    float* __restrict__ out)
{
    __shared__ uint4    s_rec0[64 * KK];        // off0,off1,w00,w01   9216B
    __shared__ float2   s_rec1[64 * KK];        // w10,w11             4608B
    __shared__ ushort_t s_a[2][2][64][32];      // [buf][j][m][c]     16384B

    int t = threadIdx.x;
    int d = blockIdx.x;                         // 1152 = 8 XCD * 144 (one batch each)
    int lb = (d & 7) * 144 + (d >> 3);
    int p0 = lb * 64;
    int b = p0 / HW;
    int rem0 = p0 - b * HW;

    // ---- bilinear records, indexed [kk*64 + m]
    for (int v = t; v < 64 * KK; v += 256) {
        int m = v & 63;
        int k = v >> 6;
        int rem = rem0 + m;
        int h = rem / W;
        int w = rem - h * W;
        const float* omb = om + (size_t)b * 27 * HW + rem;
        float offy = omb[(size_t)(2 * k) * HW];
        float offx = omb[(size_t)(2 * k + 1) * HW];
        float z    = omb[(size_t)(18 + k) * HW];
        float mval = 1.0f / (1.0f + __expf(-z));
        float py = (float)(h + k / 3 - 1) + offy;
        float px = (float)(w + k % 3 - 1) + offx;
        float fy = floorf(py), fx = floorf(px);
        int y0 = (int)fy, x0 = (int)fx;
        float wy = py - fy, wx = px - fx;
        float row0f = (1.0f - wy) * mval * ((y0 >= 0 && y0 < H) ? 1.0f : 0.0f);
        float row1f = wy * mval * ((y0 >= -1 && y0 < H - 1) ? 1.0f : 0.0f);
        int xsel = min(max(x0, 0), W - 2);
        float wxa = (x0 >= 0 && x0 < W) ? (1.0f - wx) : 0.0f;
        float wxb = (x0 >= -1 && x0 < W - 1) ? wx : 0.0f;
        int cx0 = min(max(x0, 0), W - 1);
        int cx1 = min(max(x0 + 1, 0), W - 1);
        float wA = ((cx0 == xsel) ? wxa : 0.0f) + ((cx1 == xsel) ? wxb : 0.0f);
        float wB = ((cx0 == xsel + 1) ? wxa : 0.0f) + ((cx1 == xsel + 1) ? wxb : 0.0f);
        int yc0 = min(max(y0, 0), H - 1);
        int yc1 = min(max(y0 + 1, 0), H - 1);
        uint4 r0;
        r0.x = (uint_t)((yc0 * W + xsel) * C);
        r0.y = (uint_t)((yc1 * W + xsel) * C);
        r0.z = __float_as_uint(row0f * wA);
        r0.w = __float_as_uint(row0f * wB);
        s_rec0[v] = r0;
        s_rec1[v] = make_float2(row1f * wA, row1f * wB);
    }

    float4v acc[4][4];
#pragma unroll
    for (int i = 0; i < 4; ++i)
#pragma unroll
        for (int j = 0; j < 4; ++j)
            acc[i][j] = (float4v){0.f, 0.f, 0.f, 0.f};

    const ushort_t* xtb = xt + (size_t)b * HW * C;
    int wv = t >> 6;          // wave -> n block (wv*64)
    int l  = t & 63;
    int ln = l & 15;
    int lq = l >> 4;
    int sm = t >> 2;          // staging pixel 0..63 (16 px per wave -> 64B segments)
    int sc = (t & 3) * 8;     // staging channel octet

    __syncthreads();

    uint4 L[8];
    float Wt[4];

    // phase it: kk = it>>2, channels (it&3)*64 .. +64 (j=0: +0..31, j=1: +32..63)
#define ISSUE_A(it_) do {                                                   \
        int kk_ = (it_) >> 2, q_ = (it_) & 3;                               \
        uint4 r0_ = s_rec0[kk_ * 64 + sm];                                  \
        float2 r1_ = s_rec1[kk_ * 64 + sm];                                 \
        const ushort_t* a0_ = xtb + r0_.x + q_ * 64 + sc;                   \
        const ushort_t* a1_ = xtb + r0_.y + q_ * 64 + sc;                   \
        Wt[0] = __uint_as_float(r0_.z); Wt[1] = __uint_as_float(r0_.w);     \
        Wt[2] = r1_.x; Wt[3] = r1_.y;                                       \
        L[0] = *(const uint4*)(a0_);      L[1] = *(const uint4*)(a0_ + C);  \
        L[2] = *(const uint4*)(a1_);      L[3] = *(const uint4*)(a1_ + C);  \
        L[4] = *(const uint4*)(a0_ + 32); L[5] = *(const uint4*)(a0_ + C + 32); \
        L[6] = *(const uint4*)(a1_ + 32); L[7] = *(const uint4*)(a1_ + C + 32); \
    } while (0)

#define COMBINE_WRITE(db_) do {                                             \
        _Pragma("unroll")                                                   \
        for (int j_ = 0; j_ < 2; ++j_) {                                    \
            float v0_[8], v1_[8], v2_[8], v3_[8], val_[8];                  \
            unpack8(L[j_ * 4 + 0], v0_); unpack8(L[j_ * 4 + 1], v1_);       \
            unpack8(L[j_ * 4 + 2], v2_); unpack8(L[j_ * 4 + 3], v3_);       \
            _Pragma("unroll")                                               \
            for (int e_ = 0; e_ < 8; ++e_)                                  \
                val_[e_] = v0_[e_] * Wt[0] + v1_[e_] * Wt[1]                \
                         + v2_[e_] * Wt[2] + v3_[e_] * Wt[3];               \
            uint4 pk_;                                                      \
            pk_.x = packbf2(val_[0], val_[1]);                              \
            pk_.y = packbf2(val_[2], val_[3]);                              \
            pk_.z = packbf2(val_[4], val_[5]);                              \
            pk_.w = packbf2(val_[6], val_[7]);                              \
            *(uint4*)&s_a[db_][j_][sm][sc] = pk_;                           \
        }                                                                   \
    } while (0)

    // prologue: phase 0 staged (latency exposed once)
    ISSUE_A(0);
    COMBINE_WRITE(0);

    for (int it = 0; it < 36; ++it) {
        int kk = it >> 2, q = it & 3;
        int buf = it & 1;
        __syncthreads();                 // publishes s_a[buf]; nothing in flight

        if (it < 35) ISSUE_A(it + 1);    // in flight across the MFMA section

        const ushort_t* bpk = bp + ((size_t)kk * O + wv * 64 + ln) * C + q * 64 + lq * 8;
#pragma unroll
        for (int j = 0; j < 2; ++j) {
            short8 af[4], bfr[4];
#pragma unroll
            for (int nt = 0; nt < 4; ++nt)
                bfr[nt] = *(const short8*)(bpk + (size_t)nt * 16 * C + j * 32);
#pragma unroll
            for (int mt = 0; mt < 4; ++mt)
                af[mt] = *(const short8*)&s_a[buf][j][mt * 16 + ln][lq * 8];
#pragma unroll
            for (int mt = 0; mt < 4; ++mt)
#pragma unroll
                for (int nt = 0; nt < 4; ++nt)
                    acc[mt][nt] = __builtin_amdgcn_mfma_f32_16x16x32_bf16(
                        af[mt], bfr[nt], acc[mt][nt], 0, 0, 0);
        }

        if (it < 35) COMBINE_WRITE(buf ^ 1);
    }
#undef ISSUE_A
#undef COMBINE_WRITE

    // ---- epilogue: bias + BN + ReLU
#pragma unroll
    for (int nt = 0; nt < 4; ++nt) {
        int o = wv * 64 + nt * 16 + ln;
        float scale = gamma[o] * rsqrtf(rvar[o] + EPS);
        float shift = (b_dcn[o] - rmean[o]) * scale + beta[o];
        float* po = out + ((size_t)b * O + o) * HW + rem0 + lq * 4;
#pragma unroll
        for (int mt = 0; mt < 4; ++mt) {
            float4 vv;
            vv.x = fmaxf(acc[mt][nt].x * scale + shift, 0.0f);
            vv.y = fmaxf(acc[mt][nt].y * scale + shift, 0.0f);
            vv.z = fmaxf(acc[mt][nt].z * scale + shift, 0.0f);
            vv.w = fmaxf(acc[mt][nt].w * scale + shift, 0.0f);
            *(float4*)(po + mt * 16) = vv;
        }
    }
}

extern "C" void kernel_launch(void* const* d_in, const int* in_sizes, int n_in,
                              void* d_out, int out_size, void* d_ws, size_t ws_size,
                              hipStream_t stream) {
    const float* x     = (const float*)d_in[0];
    const float* w_off = (const float*)d_in[1];
    const float* b_off = (const float*)d_in[2];
    const float* w_dcn = (const float*)d_in[3];
    const float* b_dcn = (const float*)d_in[4];
    const float* gamma = (const float*)d_in[5];
    const float* beta  = (const float*)d_in[6];
    const float* rmean = (const float*)d_in[7];
    const float* rvar  = (const float*)d_in[8];
    float* out = (float*)d_out;

    float*    om  = (float*)d_ws;                          // 1,990,656 f (7.96 MB)
    ushort_t* bpw = (ushort_t*)(om + (size_t)B * 27 * HW); // 589,824 us (1.18 MB)
    ushort_t* bow = bpw + (size_t)KK * O * C;              // 73,728 us (147 KB)
    ushort_t* xtw = bow + (size_t)32 * KK * C;             // 18,874,368 us (37.7 MB)

    hipLaunchKernelGGL(transpose_x_k, dim3(144, 4, 8), dim3(256), 0, stream,
                       x, xtw);
    hipLaunchKernelGGL(prep_b_k, dim3(2304), dim3(256), 0, stream,
                       w_dcn, bpw);
    hipLaunchKernelGGL(prep_bo_k, dim3(288), dim3(256), 0, stream,
                       w_off, bow);
    hipLaunchKernelGGL(offset_mfma_k, dim3(73728 / 128), dim3(256), 0, stream,
                       xtw, bow, b_off, om);
    hipLaunchKernelGGL(dcn_main_k, dim3(73728 / 64), dim3(256), 0, stream,
                       xtw, om, bpw, b_dcn, gamma, beta, rmean, rvar, out);
}

// Round 6
// 459.012 us; speedup vs baseline: 1.2469x; 1.0388x over previous
//
#include <hip/hip_runtime.h>
#include <hip/hip_bf16.h>
#include <cstdint>
#include <cstddef>

#define H 96
#define W 96
#define HW 9216
#define C 256
#define B 8
#define O 256
#define KK 9
#define EPS 1e-5f

typedef __attribute__((ext_vector_type(8))) short short8;
typedef __attribute__((ext_vector_type(4))) float float4v;
typedef __attribute__((ext_vector_type(2))) float float2v;
typedef unsigned short ushort_t;
typedef unsigned int uint_t;

// ---------------- Kernel 1: transpose x (B,C,HW) fp32 -> x_t (B,HW,C) bf16
__global__ __launch_bounds__(256) void transpose_x_k(
    const float* __restrict__ x, ushort_t* __restrict__ xt)
{
    __shared__ float tile[64][65];
    int t = threadIdx.x;
    int p0 = blockIdx.x * 64;
    int c0 = blockIdx.y * 64;
    int b  = blockIdx.z;
    {
        int tx = t & 63, ty = t >> 6;
        const float* xb = x + ((size_t)b * C + c0 + ty) * HW + p0 + tx;
#pragma unroll
        for (int i = 0; i < 64; i += 4)
            tile[ty + i][tx] = xb[(size_t)i * HW];
    }
    __syncthreads();
    {
        int tc = t & 31, tp = t >> 5;
        ushort_t* xtb = xt + ((size_t)b * HW + p0) * C + c0;
#pragma unroll
        for (int i = 0; i < 64; i += 8) {
            int p = tp + i;
            float a  = tile[2 * tc][p];
            float bb = tile[2 * tc + 1][p];
            __hip_bfloat162 h2 = __float22bfloat162_rn(make_float2(a, bb));
            uint_t u;
            __builtin_memcpy(&u, &h2, 4);
            *reinterpret_cast<uint_t*>(&xtb[(size_t)p * C + 2 * tc]) = u;
        }
    }
}

// ---------------- Kernel 2: w_dcn (O, C, KK) fp32 -> Bp[kk][o][c] bf16
__global__ __launch_bounds__(256) void prep_b_k(
    const float* __restrict__ wd, ushort_t* __restrict__ bp)
{
    int idx = blockIdx.x * 256 + threadIdx.x;
    int kk = idx / (O * C);
    int r = idx - kk * O * C;
    int o = r >> 8, c = r & 255;
    float v = wd[((size_t)o * C + c) * KK + kk];
    __hip_bfloat16 hh = __float2bfloat16(v);
    ushort_t u;
    __builtin_memcpy(&u, &hh, 2);
    bp[idx] = u;
}

// ---------------- Kernel 3: w_off (27, C, 3, 3) fp32 -> bo[n=32][kk][c] bf16
__global__ __launch_bounds__(256) void prep_bo_k(
    const float* __restrict__ wo, ushort_t* __restrict__ bo)
{
    int idx = blockIdx.x * 256 + threadIdx.x;
    int n = idx / (KK * C);
    int r = idx - n * KK * C;
    int kk = r >> 8, c = r & 255;
    float v = (n < 27) ? wo[((size_t)n * C + c) * KK + kk] : 0.0f;
    __hip_bfloat16 hh = __float2bfloat16(v);
    ushort_t u;
    __builtin_memcpy(&u, &hh, 2);
    bo[idx] = u;
}

// ---------------- Kernel 4: offset conv via MFMA (XCD-swizzled, branch-free loads)
__global__ __launch_bounds__(256) void offset_mfma_k(
    const ushort_t* __restrict__ xt, const ushort_t* __restrict__ bo,
    const float* __restrict__ b_off, float* __restrict__ om)
{
    int t = threadIdx.x;
    int wv = t >> 6, l = t & 63;
    int ln = l & 15, lq = l >> 4;
    int d = blockIdx.x;                      // 576 = 8 XCD * 72 (one batch each)
    int lb = (d & 7) * 72 + (d >> 3);
    int p0 = lb * 128;
    int b = p0 / HW;
    int rem0w = p0 - b * HW + wv * 32;
    const ushort_t* xtb = xt + (size_t)b * HW * C;

    int hh0[2], ww0[2];
#pragma unroll
    for (int mt = 0; mt < 2; ++mt) {
        int rem = rem0w + mt * 16 + ln;
        hh0[mt] = rem / W;
        ww0[mt] = rem - hh0[mt] * W;
    }

    float4v acc[2][2];
#pragma unroll
    for (int i = 0; i < 2; ++i)
#pragma unroll
        for (int j = 0; j < 2; ++j) acc[i][j] = (float4v){0.f, 0.f, 0.f, 0.f};

#pragma unroll
    for (int kk = 0; kk < KK; ++kk) {
        int dy = kk / 3 - 1, dx = kk % 3 - 1;
        const ushort_t* ap[2];
        uint_t msk[2];
#pragma unroll
        for (int mt = 0; mt < 2; ++mt) {
            int hh = hh0[mt] + dy, ww = ww0[mt] + dx;
            bool ok = (hh >= 0) & (hh < H) & (ww >= 0) & (ww < W);
            msk[mt] = ok ? 0xffffffffu : 0u;
            int hc = min(max(hh, 0), H - 1);
            int wc = min(max(ww, 0), W - 1);
            ap[mt] = xtb + (size_t)(hc * W + wc) * C + lq * 8;
        }
        const ushort_t* bp0 = bo + ((size_t)(0 * 16 + ln) * KK + kk) * C + lq * 8;
        const ushort_t* bp1 = bo + ((size_t)(1 * 16 + ln) * KK + kk) * C + lq * 8;
#pragma unroll
        for (int cc = 0; cc < 8; ++cc) {
            int c0 = cc * 32;
            short8 af[2];
#pragma unroll
            for (int mt = 0; mt < 2; ++mt) {
                uint4 u = *(const uint4*)(ap[mt] + c0);
                u.x &= msk[mt]; u.y &= msk[mt]; u.z &= msk[mt]; u.w &= msk[mt];
                __builtin_memcpy(&af[mt], &u, 16);
            }
            short8 bf0 = *(const short8*)(bp0 + c0);
            short8 bf1 = *(const short8*)(bp1 + c0);
#pragma unroll
            for (int mt = 0; mt < 2; ++mt) {
                acc[mt][0] = __builtin_amdgcn_mfma_f32_16x16x32_bf16(af[mt], bf0, acc[mt][0], 0, 0, 0);
                acc[mt][1] = __builtin_amdgcn_mfma_f32_16x16x32_bf16(af[mt], bf1, acc[mt][1], 0, 0, 0);
            }
        }
    }

    float* omb = om + (size_t)b * 27 * HW + rem0w;
#pragma unroll
    for (int nt = 0; nt < 2; ++nt) {
        int oc = nt * 16 + ln;
        if (oc < 27) {
            float bv = b_off[oc];
            float* po = omb + (size_t)oc * HW + lq * 4;
#pragma unroll
            for (int mt = 0; mt < 2; ++mt) {
                float4 v;
                v.x = acc[mt][nt].x + bv;
                v.y = acc[mt][nt].y + bv;
                v.z = acc[mt][nt].z + bv;
                v.w = acc[mt][nt].w + bv;
                *(float4*)(po + mt * 16) = v;
            }
        }
    }
}

__device__ __forceinline__ float2v up2(uint_t u) {
    float2v r;
    r.x = __uint_as_float(u << 16);
    r.y = __uint_as_float(u & 0xffff0000u);
    return r;
}

__device__ __forceinline__ uint_t packbf2(float a, float b) {
    __hip_bfloat162 h2 = __float22bfloat162_rn(make_float2(a, b));
    uint_t u;
    __builtin_memcpy(&u, &h2, 4);
    return u;
}

// ---------------- Kernel 5: deformable conv main
// Phase = one tap kk (256 ch), 9 phases, dbuf 2x32KB, ONE barrier per phase.
// Chunk loop interleaves: stage-loads(ci) | B-prefetch(ci+1) | MFMA(ci) | combine(ci).
__global__ __launch_bounds__(256) void dcn_main_k(
    const ushort_t* __restrict__ xt, const float* __restrict__ om,
    const ushort_t* __restrict__ bp, const float* __restrict__ b_dcn,
    const float* __restrict__ gamma, const float* __restrict__ beta,
    const float* __restrict__ rmean, const float* __restrict__ rvar,
    float* __restrict__ out)
{
    __shared__ uint4    s_rec0[64 * KK];         // off0,off1,w00,w01   9216B
    __shared__ float2   s_rec1[64 * KK];         // w10,w11             4608B
    __shared__ ushort_t s_a[2][8][64][32];       // [buf][ci][m][c]    65536B

    int t = threadIdx.x;
    int d = blockIdx.x;                          // 1152 = 8 XCD * 144
    int lb = (d & 7) * 144 + (d >> 3);
    int p0 = lb * 64;
    int b = p0 / HW;
    int rem0 = p0 - b * HW;

    // ---- bilinear records, indexed [kk*64 + m]
    for (int v = t; v < 64 * KK; v += 256) {
        int m = v & 63;
        int k = v >> 6;
        int rem = rem0 + m;
        int h = rem / W;
        int w = rem - h * W;
        const float* omb = om + (size_t)b * 27 * HW + rem;
        float offy = omb[(size_t)(2 * k) * HW];
        float offx = omb[(size_t)(2 * k + 1) * HW];
        float z    = omb[(size_t)(18 + k) * HW];
        float mval = 1.0f / (1.0f + __expf(-z));
        float py = (float)(h + k / 3 - 1) + offy;
        float px = (float)(w + k % 3 - 1) + offx;
        float fy = floorf(py), fx = floorf(px);
        int y0 = (int)fy, x0 = (int)fx;
        float wy = py - fy, wx = px - fx;
        float row0f = (1.0f - wy) * mval * ((y0 >= 0 && y0 < H) ? 1.0f : 0.0f);
        float row1f = wy * mval * ((y0 >= -1 && y0 < H - 1) ? 1.0f : 0.0f);
        int xsel = min(max(x0, 0), W - 2);
        float wxa = (x0 >= 0 && x0 < W) ? (1.0f - wx) : 0.0f;
        float wxb = (x0 >= -1 && x0 < W - 1) ? wx : 0.0f;
        int cx0 = min(max(x0, 0), W - 1);
        int cx1 = min(max(x0 + 1, 0), W - 1);
        float wA = ((cx0 == xsel) ? wxa : 0.0f) + ((cx1 == xsel) ? wxb : 0.0f);
        float wB = ((cx0 == xsel + 1) ? wxa : 0.0f) + ((cx1 == xsel + 1) ? wxb : 0.0f);
        int yc0 = min(max(y0, 0), H - 1);
        int yc1 = min(max(y0 + 1, 0), H - 1);
        uint4 r0;
        r0.x = (uint_t)((yc0 * W + xsel) * C);
        r0.y = (uint_t)((yc1 * W + xsel) * C);
        r0.z = __float_as_uint(row0f * wA);
        r0.w = __float_as_uint(row0f * wB);
        s_rec0[v] = r0;
        s_rec1[v] = make_float2(row1f * wA, row1f * wB);
    }

    float4v acc[4][4];
#pragma unroll
    for (int i = 0; i < 4; ++i)
#pragma unroll
        for (int j = 0; j < 4; ++j)
            acc[i][j] = (float4v){0.f, 0.f, 0.f, 0.f};

    const ushort_t* xtb = xt + (size_t)b * HW * C;
    int wv = t >> 6;          // wave -> n block (wv*64)
    int l  = t & 63;
    int ln = l & 15;
    int lq = l >> 4;
    int sm = t >> 2;          // staging pixel 0..63
    int sc = (t & 3) * 8;     // staging channel octet

    __syncthreads();

    // combine one 8-channel group from 4 corner uint4s -> packed bf16 uint4
#define COMBINE(L0_, L1_, L2_, L3_, W_, dst_) do {                          \
        uint4 pk_;                                                          \
        float2v r0_ = up2((L0_).x) * (W_)[0] + up2((L1_).x) * (W_)[1]       \
                    + up2((L2_).x) * (W_)[2] + up2((L3_).x) * (W_)[3];      \
        float2v r1_ = up2((L0_).y) * (W_)[0] + up2((L1_).y) * (W_)[1]       \
                    + up2((L2_).y) * (W_)[2] + up2((L3_).y) * (W_)[3];      \
        float2v r2_ = up2((L0_).z) * (W_)[0] + up2((L1_).z) * (W_)[1]       \
                    + up2((L2_).z) * (W_)[2] + up2((L3_).z) * (W_)[3];      \
        float2v r3_ = up2((L0_).w) * (W_)[0] + up2((L1_).w) * (W_)[1]       \
                    + up2((L2_).w) * (W_)[2] + up2((L3_).w) * (W_)[3];      \
        pk_.x = packbf2(r0_.x, r0_.y);                                      \
        pk_.y = packbf2(r1_.x, r1_.y);                                      \
        pk_.z = packbf2(r2_.x, r2_.y);                                      \
        pk_.w = packbf2(r3_.x, r3_.y);                                      \
        *(uint4*)(dst_) = pk_;                                              \
    } while (0)

    // ---- prologue: stage phase 0 into buf 0
    {
        uint4 r0 = s_rec0[sm];
        float2 r1 = s_rec1[sm];
        const ushort_t* a0 = xtb + r0.x + sc;
        const ushort_t* a1 = xtb + r0.y + sc;
        float Wt[4] = {__uint_as_float(r0.z), __uint_as_float(r0.w), r1.x, r1.y};
#pragma unroll
        for (int ci = 0; ci < 8; ++ci) {
            uint4 L0 = *(const uint4*)(a0 + ci * 32);
            uint4 L1 = *(const uint4*)(a0 + ci * 32 + C);
            uint4 L2 = *(const uint4*)(a1 + ci * 32);
            uint4 L3 = *(const uint4*)(a1 + ci * 32 + C);
            COMBINE(L0, L1, L2, L3, Wt, &s_a[0][ci][sm][sc]);
        }
    }
    __syncthreads();

    for (int kk = 0; kk < KK; ++kk) {
        int rb = kk & 1;
        int wb = rb ^ 1;
        bool more = (kk < KK - 1);

        // next-phase staging pointers/weights
        const ushort_t* a0n = xtb;
        const ushort_t* a1n = xtb;
        float Wn[4] = {0.f, 0.f, 0.f, 0.f};
        if (more) {
            uint4 r0 = s_rec0[(kk + 1) * 64 + sm];
            float2 r1 = s_rec1[(kk + 1) * 64 + sm];
            a0n = xtb + r0.x + sc;
            a1n = xtb + r0.y + sc;
            Wn[0] = __uint_as_float(r0.z); Wn[1] = __uint_as_float(r0.w);
            Wn[2] = r1.x; Wn[3] = r1.y;
        }

        const ushort_t* bpk = bp + ((size_t)kk * O + wv * 64 + ln) * C + lq * 8;
        short8 bfr[4], bfrN[4];
#pragma unroll
        for (int nt = 0; nt < 4; ++nt)
            bfr[nt] = *(const short8*)(bpk + (size_t)nt * 16 * C);   // chunk 0

#pragma unroll
        for (int ci = 0; ci < 8; ++ci) {
            // stage-loads for next phase, chunk ci (in flight across MFMA below)
            uint4 L0, L1, L2, L3;
            if (more) {
                L0 = *(const uint4*)(a0n + ci * 32);
                L1 = *(const uint4*)(a0n + ci * 32 + C);
                L2 = *(const uint4*)(a1n + ci * 32);
                L3 = *(const uint4*)(a1n + ci * 32 + C);
            }
            // B prefetch for chunk ci+1
            if (ci < 7) {
#pragma unroll
                for (int nt = 0; nt < 4; ++nt)
                    bfrN[nt] = *(const short8*)(bpk + (size_t)nt * 16 * C + (ci + 1) * 32);
            }
            // MFMA on current buffer, chunk ci
            short8 af[4];
#pragma unroll
            for (int mt = 0; mt < 4; ++mt)
                af[mt] = *(const short8*)&s_a[rb][ci][mt * 16 + ln][lq * 8];
#pragma unroll
            for (int mt = 0; mt < 4; ++mt)
#pragma unroll
                for (int nt = 0; nt < 4; ++nt)
                    acc[mt][nt] = __builtin_amdgcn_mfma_f32_16x16x32_bf16(
                        af[mt], bfr[nt], acc[mt][nt], 0, 0, 0);
            // combine + publish next phase chunk
            if (more)
                COMBINE(L0, L1, L2, L3, Wn, &s_a[wb][ci][sm][sc]);
#pragma unroll
            for (int nt = 0; nt < 4; ++nt)
                bfr[nt] = bfrN[nt];
        }
        __syncthreads();
    }
#undef COMBINE

    // ---- epilogue: bias + BN + ReLU
#pragma unroll
    for (int nt = 0; nt < 4; ++nt) {
        int o = wv * 64 + nt * 16 + ln;
        float scale = gamma[o] * rsqrtf(rvar[o] + EPS);
        float shift = (b_dcn[o] - rmean[o]) * scale + beta[o];
        float* po = out + ((size_t)b * O + o) * HW + rem0 + lq * 4;
#pragma unroll
        for (int mt = 0; mt < 4; ++mt) {
            float4 vv;
            vv.x = fmaxf(acc[mt][nt].x * scale + shift, 0.0f);
            vv.y = fmaxf(acc[mt][nt].y * scale + shift, 0.0f);
            vv.z = fmaxf(acc[mt][nt].z * scale + shift, 0.0f);
            vv.w = fmaxf(acc[mt][nt].w * scale + shift, 0.0f);
            *(float4*)(po + mt * 16) = vv;
        }
    }
}

extern "C" void kernel_launch(void* const* d_in, const int* in_sizes, int n_in,
                              void* d_out, int out_size, void* d_ws, size_t ws_size,
                              hipStream_t stream) {
    const float* x     = (const float*)d_in[0];
    const float* w_off = (const float*)d_in[1];
    const float* b_off = (const float*)d_in[2];
    const float* w_dcn = (const float*)d_in[3];
    const float* b_dcn = (const float*)d_in[4];
    const float* gamma = (const float*)d_in[5];
    const float* beta  = (const float*)d_in[6];
    const float* rmean = (const float*)d_in[7];
    const float* rvar  = (const float*)d_in[8];
    float* out = (float*)d_out;

    float*    om  = (float*)d_ws;                          // 1,990,656 f (7.96 MB)
    ushort_t* bpw = (ushort_t*)(om + (size_t)B * 27 * HW); // 589,824 us (1.18 MB)
    ushort_t* bow = bpw + (size_t)KK * O * C;              // 73,728 us (147 KB)
    ushort_t* xtw = bow + (size_t)32 * KK * C;             // 18,874,368 us (37.7 MB)

    hipLaunchKernelGGL(transpose_x_k, dim3(144, 4, 8), dim3(256), 0, stream,
                       x, xtw);
    hipLaunchKernelGGL(prep_b_k, dim3(2304), dim3(256), 0, stream,
                       w_dcn, bpw);
    hipLaunchKernelGGL(prep_bo_k, dim3(288), dim3(256), 0, stream,
                       w_off, bow);
    hipLaunchKernelGGL(offset_mfma_k, dim3(73728 / 128), dim3(256), 0, stream,
                       xtw, bow, b_off, om);
    hipLaunchKernelGGL(dcn_main_k, dim3(73728 / 64), dim3(256), 0, stream,
                       xtw, om, bpw, b_dcn, gamma, beta, rmean, rvar, out);
}